// Round 1
// baseline (7532.722 us; speedup 1.0000x reference)
//
#include <hip/hip_runtime.h>
#include <math.h>

// Problem constants
#define BB 16
#define LL 5000
#define DIN 12
#define HH 256
#define NN 32
#define NLAYER 4
#define LC 125              // chunk length
#define NCH 40              // number of chunks (40*125 = 5000)
#define NROWS (BB*LL)       // 80000 rows of H=256

#define SSIZE ((size_t)NCH*BB*HH*NN*2)   // chunk-state buffer (complex) = 10,485,760 floats
#define PSTRIDE (HH*NN*2)                // per-layer param stride = 16384 floats

// ---------------------------------------------------------------------------
// Per-layer SSM parameter precompute: w = exp(dt*A), Ct2 = 2*C*(w-1)/A, wLc = w^LC
// layout: [layer][h][n][2]
// ---------------------------------------------------------------------------
__global__ __launch_bounds__(256) void param_kernel(
    const float* __restrict__ log_dt, const float* __restrict__ logA_re,
    const float* __restrict__ A_im, const float* __restrict__ Cp,
    float* __restrict__ Wp, float* __restrict__ Ct2, float* __restrict__ WLc) {
  int gid = blockIdx.x * 256 + threadIdx.x;       // NLAYER*HH*NN = 32768
  if (gid >= NLAYER * HH * NN) return;
  int l = gid / (HH * NN);
  int hn = gid % (HH * NN);
  int h = hn / NN;
  float dt = expf(log_dt[l * HH + h]);
  float Are = -expf(logA_re[gid]);
  float Aim = A_im[gid];
  float are = Are * dt, aim = Aim * dt;
  float e = expf(are);
  float wre = e * cosf(aim), wim = e * sinf(aim);
  float Crev = Cp[2 * gid], Cimv = Cp[2 * gid + 1];
  float nre = wre - 1.0f, nim = wim;
  float tre = Crev * nre - Cimv * nim;
  float tim = Crev * nim + Cimv * nre;
  float inv = 1.0f / (Are * Are + Aim * Aim);
  float ctre = (tre * Are + tim * Aim) * inv;     // t * conj(A) / |A|^2
  float ctim = (tim * Are - tre * Aim) * inv;
  Wp[2 * gid] = wre; Wp[2 * gid + 1] = wim;
  Ct2[2 * gid] = 2.0f * ctre; Ct2[2 * gid + 1] = 2.0f * ctim;
  float eL = expf(are * (float)LC);
  float ang = aim * (float)LC;
  WLc[2 * gid] = eL * cosf(ang);
  WLc[2 * gid + 1] = eL * sinf(ang);
}

// ---------------------------------------------------------------------------
// Input projection: X = x @ W_in + b_in   (80000x12 @ 12x256)
// One block per row-iteration; thread = output channel h. x row is wave-uniform.
// ---------------------------------------------------------------------------
__global__ __launch_bounds__(256) void proj_kernel(
    const float* __restrict__ x, const float* __restrict__ Win,
    const float* __restrict__ bin, float* __restrict__ X) {
  int h = threadIdx.x;
  float w[DIN];
#pragma unroll
  for (int k = 0; k < DIN; k++) w[k] = Win[k * HH + h];
  float bias = bin[h];
  for (int row = blockIdx.x; row < NROWS; row += gridDim.x) {
    float acc = bias;
#pragma unroll
    for (int k = 0; k < DIN; k++) acc = fmaf(x[row * DIN + k], w[k], acc);
    X[(size_t)row * HH + h] = acc;
  }
}

// ---------------------------------------------------------------------------
// LayerNorm over H=256. One row per wave (64 lanes x float4), 4 rows/block.
// ---------------------------------------------------------------------------
__global__ __launch_bounds__(256) void ln_kernel(
    const float* __restrict__ in, float* __restrict__ out,
    const float* __restrict__ g, const float* __restrict__ b) {
  int wave = threadIdx.x >> 6, lane = threadIdx.x & 63;
  int row = blockIdx.x * 4 + wave;
  const float4 v = ((const float4*)(in + (size_t)row * HH))[lane];
  float s = v.x + v.y + v.z + v.w;
  float q = v.x * v.x + v.y * v.y + v.z * v.z + v.w * v.w;
#pragma unroll
  for (int m = 1; m < 64; m <<= 1) { s += __shfl_xor(s, m); q += __shfl_xor(q, m); }
  float mean = s * (1.0f / HH);
  float var = q * (1.0f / HH) - mean * mean;
  float rstd = rsqrtf(var + 1e-5f);
  float4 gg = ((const float4*)g)[lane];
  float4 bb = ((const float4*)b)[lane];
  float4 o;
  o.x = (v.x - mean) * rstd * gg.x + bb.x;
  o.y = (v.y - mean) * rstd * gg.y + bb.y;
  o.z = (v.z - mean) * rstd * gg.z + bb.z;
  o.w = (v.w - mean) * rstd * gg.w + bb.w;
  ((float4*)(out + (size_t)row * HH))[lane] = o;
}

// ---------------------------------------------------------------------------
// Scan pass A: per (chunk c, batch b, channel h) run the 32 complex recurrences
// from zero state over Lc steps; store end-of-chunk states.
// ---------------------------------------------------------------------------
__global__ __launch_bounds__(256, 3) void scanA_kernel(
    const float* __restrict__ Z, float* __restrict__ S, const float* __restrict__ Wp) {
  int c = blockIdx.x, b = blockIdx.y, h = threadIdx.x;
  float wre[NN], wim[NN], sre[NN], sim[NN];
  const float* wp = Wp + h * (NN * 2);
#pragma unroll
  for (int n = 0; n < NN; n++) {
    wre[n] = wp[2 * n]; wim[n] = wp[2 * n + 1];
    sre[n] = 0.0f; sim[n] = 0.0f;
  }
  size_t base = ((size_t)b * LL + (size_t)c * LC) * HH + h;
  float u = Z[base];
  for (int t = 0; t < LC; t++) {
    float un = Z[base + (size_t)(t + 1 < LC ? t + 1 : t) * HH];  // prefetch
#pragma unroll
    for (int n = 0; n < NN; n++) {
      float tr = fmaf(wre[n], sre[n], u);
      tr = fmaf(-wim[n], sim[n], tr);
      float ti = fmaf(wim[n], sre[n], wre[n] * sim[n]);
      sre[n] = tr; sim[n] = ti;
    }
    u = un;
  }
  float* sp = S + (((size_t)c * BB + b) * HH + h) * (NN * 2);
#pragma unroll
  for (int n = 0; n < NN; n++) { sp[2 * n] = sre[n]; sp[2 * n + 1] = sim[n]; }
}

// ---------------------------------------------------------------------------
// Scan pass B: serial scan over chunks per (b,h,n): convert local end-states
// into carry-in states (in place).  carry' = wLc*carry + local ; slot <- carry.
// ---------------------------------------------------------------------------
__global__ __launch_bounds__(256) void combine_kernel(
    float* __restrict__ S, const float* __restrict__ WLc) {
  int tid = blockIdx.x * 256 + threadIdx.x;   // BB*HH*NN = 131072
  int b = tid / (HH * NN);
  int hn = tid % (HH * NN);
  float wre = WLc[2 * hn], wim = WLc[2 * hn + 1];
  float cre = 0.0f, cim = 0.0f;
  for (int c = 0; c < NCH; c++) {
    size_t idx = (((size_t)c * BB + b) * (HH * NN) + hn) * 2;
    float vre = S[idx], vim = S[idx + 1];
    S[idx] = cre; S[idx + 1] = cim;
    float nre2 = fmaf(wre, cre, vre) - wim * cim;
    float nim2 = fmaf(wre, cim, vim) + wim * cre;
    cre = nre2; cim = nim2;
  }
}

// ---------------------------------------------------------------------------
// Scan pass C: replay recurrence with carry-in state; y = 2Re(sum Ct s) + u*D;
// apply tanh-GELU; write activations Y.
// ---------------------------------------------------------------------------
__global__ __launch_bounds__(256, 2) void scanC_kernel(
    const float* __restrict__ Z, const float* __restrict__ S,
    const float* __restrict__ Wp, const float* __restrict__ Ct2,
    const float* __restrict__ Dv, float* __restrict__ Y) {
  int c = blockIdx.x, b = blockIdx.y, h = threadIdx.x;
  float wre[NN], wim[NN], cre[NN], cim[NN], sre[NN], sim[NN];
  const float* wp = Wp + h * (NN * 2);
  const float* cp = Ct2 + h * (NN * 2);
  const float* sp = S + (((size_t)c * BB + b) * HH + h) * (NN * 2);
#pragma unroll
  for (int n = 0; n < NN; n++) {
    wre[n] = wp[2 * n]; wim[n] = wp[2 * n + 1];
    cre[n] = cp[2 * n]; cim[n] = cp[2 * n + 1];
    sre[n] = sp[2 * n]; sim[n] = sp[2 * n + 1];
  }
  float d = Dv[h];
  size_t base = ((size_t)b * LL + (size_t)c * LC) * HH + h;
  float u = Z[base];
  for (int t = 0; t < LC; t++) {
    float un = Z[base + (size_t)(t + 1 < LC ? t + 1 : t) * HH];  // prefetch
    float acc0 = u * d, acc1 = 0.0f;
#pragma unroll
    for (int n = 0; n < NN; n++) {
      float tr = fmaf(wre[n], sre[n], u);
      tr = fmaf(-wim[n], sim[n], tr);
      float ti = fmaf(wim[n], sre[n], wre[n] * sim[n]);
      sre[n] = tr; sim[n] = ti;
      if (n & 1) { acc1 = fmaf(cre[n], tr, acc1); acc1 = fmaf(-cim[n], ti, acc1); }
      else       { acc0 = fmaf(cre[n], tr, acc0); acc0 = fmaf(-cim[n], ti, acc0); }
    }
    float a = acc0 + acc1;
    // tanh-approx GELU (jax.nn.gelu default)
    float t3 = a * a * a;
    float inner = 0.7978845608028654f * (a + 0.044715f * t3);
    float y = 0.5f * a * (1.0f + tanhf(inner));
    Y[base + (size_t)t * HH] = y;
    u = un;
  }
}

// ---------------------------------------------------------------------------
// GLU FFN: G = Y @ W_glu + b_glu (80000x256 @ 256x512), out = G1*sigmoid(G2)+Z.
// fp32 LDS-tiled GEMM: 64 rows x 128 cols (64 first-half + matching 64 second-
// half columns so GLU pairs live in-register), BK=16, 256 threads, 4x8 micro.
// ---------------------------------------------------------------------------
__global__ __launch_bounds__(256) void gemm_glu_kernel(
    const float* __restrict__ A, const float* __restrict__ W,
    const float* __restrict__ bg, const float* __restrict__ Z,
    float* __restrict__ X) {
  __shared__ float a_s[16][68];   // [k][m], pad 68 -> 2-way-max bank alias
  __shared__ float b_s[16][128];  // [k][j]; j<64: cols c0+j, j>=64: cols 256+c0+(j-64)
  int r0 = blockIdx.x * 64;
  int c0 = blockIdx.y * 64;
  int t = threadIdx.x;
  int tx = t & 15, ty = t >> 4;
  float acc[4][8];
#pragma unroll
  for (int i = 0; i < 4; i++)
#pragma unroll
    for (int j = 0; j < 8; j++) acc[i][j] = 0.0f;
  int lk = t & 15, lr = t >> 4;
  for (int kt = 0; kt < HH; kt += 16) {
#pragma unroll
    for (int i = 0; i < 4; i++) {
      int m = lr + 16 * i;
      a_s[lk][m] = A[(size_t)(r0 + m) * HH + kt + lk];
    }
#pragma unroll
    for (int i = 0; i < 8; i++) {
      int idx = t + 256 * i;
      int k = idx >> 7, jj = idx & 127;
      int col = (jj < 64) ? (c0 + jj) : (256 + c0 + (jj - 64));
      b_s[k][jj] = W[(kt + k) * 512 + col];
    }
    __syncthreads();
#pragma unroll
    for (int k = 0; k < 16; k++) {
      float4 av = *(const float4*)&a_s[k][ty * 4];
      float4 b0 = *(const float4*)&b_s[k][tx * 4];
      float4 b1 = *(const float4*)&b_s[k][64 + tx * 4];
      float a4[4] = {av.x, av.y, av.z, av.w};
      float bb[8] = {b0.x, b0.y, b0.z, b0.w, b1.x, b1.y, b1.z, b1.w};
#pragma unroll
      for (int i = 0; i < 4; i++)
#pragma unroll
        for (int j = 0; j < 8; j++) acc[i][j] = fmaf(a4[i], bb[j], acc[i][j]);
    }
    __syncthreads();
  }
#pragma unroll
  for (int i = 0; i < 4; i++) {
    int row = r0 + ty * 4 + i;
#pragma unroll
    for (int j = 0; j < 4; j++) {
      int h = c0 + tx * 4 + j;
      float g1 = acc[i][j] + bg[h];
      float g2 = acc[i][4 + j] + bg[256 + h];
      float sig = 1.0f / (1.0f + expf(-g2));
      X[(size_t)row * HH + h] = fmaf(g1, sig, Z[(size_t)row * HH + h]);
    }
  }
}

// ---------------------------------------------------------------------------
extern "C" void kernel_launch(void* const* d_in, const int* in_sizes, int n_in,
                              void* d_out, int out_size, void* d_ws, size_t ws_size,
                              hipStream_t stream) {
  const float* x      = (const float*)d_in[0];
  const float* Win    = (const float*)d_in[1];
  const float* bin    = (const float*)d_in[2];
  const float* ln_g   = (const float*)d_in[3];
  const float* ln_b   = (const float*)d_in[4];
  const float* log_dt = (const float*)d_in[5];
  const float* logA   = (const float*)d_in[6];
  const float* A_im   = (const float*)d_in[7];
  const float* Cp     = (const float*)d_in[8];
  const float* Dv     = (const float*)d_in[9];
  const float* Wglu   = (const float*)d_in[10];
  const float* bglu   = (const float*)d_in[11];
  const float* fn_g   = (const float*)d_in[12];
  const float* fn_b   = (const float*)d_in[13];
  float* out = (float*)d_out;
  float* ws = (float*)d_ws;

  float* X   = ws;                               // 20,480,000 floats
  float* Z   = X + (size_t)NROWS * HH;           // 20,480,000 floats
  float* S   = Z + (size_t)NROWS * HH;           // 10,485,760 floats
  float* Wp  = S + SSIZE;                        // 65,536 floats
  float* Ct2 = Wp + (size_t)NLAYER * PSTRIDE;    // 65,536 floats
  float* WLc = Ct2 + (size_t)NLAYER * PSTRIDE;   // 65,536 floats
  float* Y   = out;                              // reuse d_out as activation scratch

  param_kernel<<<(NLAYER * HH * NN) / 256, 256, 0, stream>>>(log_dt, logA, A_im, Cp, Wp, Ct2, WLc);
  proj_kernel<<<2048, 256, 0, stream>>>(x, Win, bin, X);

  for (int l = 0; l < NLAYER; l++) {
    ln_kernel<<<NROWS / 4, 256, 0, stream>>>(X, Z, ln_g + l * HH, ln_b + l * HH);
    scanA_kernel<<<dim3(NCH, BB), 256, 0, stream>>>(Z, S, Wp + (size_t)l * PSTRIDE);
    combine_kernel<<<(BB * HH * NN) / 256, 256, 0, stream>>>(S, WLc + (size_t)l * PSTRIDE);
    scanC_kernel<<<dim3(NCH, BB), 256, 0, stream>>>(Z, S, Wp + (size_t)l * PSTRIDE,
                                                    Ct2 + (size_t)l * PSTRIDE, Dv + l * HH, Y);
    gemm_glu_kernel<<<dim3(NROWS / 64, 4), 256, 0, stream>>>(
        Y, Wglu + (size_t)l * HH * 2 * HH, bglu + l * 2 * HH, Z, X);
  }
  ln_kernel<<<NROWS / 4, 256, 0, stream>>>(X, out, fn_g, fn_b);
}

// Round 2
// 2492.001 us; speedup vs baseline: 3.0228x; 3.0228x over previous
//
#include <hip/hip_runtime.h>
#include <math.h>

// Problem constants
#define BB 16
#define LL 5000
#define DIN 12
#define HH 256
#define NN 32
#define NLAYER 4
#define LC 125              // chunk length
#define NCH 40              // number of chunks (40*125 = 5000)
#define NROWS (BB*LL)       // 80000 rows of H=256

#define SSIZE ((size_t)NCH*BB*HH*NN*2)   // chunk-state buffer (complex) = 10,485,760 floats
#define PSTRIDE (HH*NN*2)                // per-layer param stride = 16384 floats

// ---------------------------------------------------------------------------
// Per-layer SSM parameter precompute: w = exp(dt*A), Ct2 = 2*C*(w-1)/A, wLc = w^LC
// layout: [layer][h][n][2]
// ---------------------------------------------------------------------------
__global__ __launch_bounds__(256) void param_kernel(
    const float* __restrict__ log_dt, const float* __restrict__ logA_re,
    const float* __restrict__ A_im, const float* __restrict__ Cp,
    float* __restrict__ Wp, float* __restrict__ Ct2, float* __restrict__ WLc) {
  int gid = blockIdx.x * 256 + threadIdx.x;       // NLAYER*HH*NN = 32768
  if (gid >= NLAYER * HH * NN) return;
  int l = gid / (HH * NN);
  int hn = gid % (HH * NN);
  int h = hn / NN;
  float dt = expf(log_dt[l * HH + h]);
  float Are = -expf(logA_re[gid]);
  float Aim = A_im[gid];
  float are = Are * dt, aim = Aim * dt;
  float e = expf(are);
  float wre = e * cosf(aim), wim = e * sinf(aim);
  float Crev = Cp[2 * gid], Cimv = Cp[2 * gid + 1];
  float nre = wre - 1.0f, nim = wim;
  float tre = Crev * nre - Cimv * nim;
  float tim = Crev * nim + Cimv * nre;
  float inv = 1.0f / (Are * Are + Aim * Aim);
  float ctre = (tre * Are + tim * Aim) * inv;     // t * conj(A) / |A|^2
  float ctim = (tim * Are - tre * Aim) * inv;
  Wp[2 * gid] = wre; Wp[2 * gid + 1] = wim;
  Ct2[2 * gid] = 2.0f * ctre; Ct2[2 * gid + 1] = 2.0f * ctim;
  float eL = expf(are * (float)LC);
  float ang = aim * (float)LC;
  WLc[2 * gid] = eL * cosf(ang);
  WLc[2 * gid + 1] = eL * sinf(ang);
}

// ---------------------------------------------------------------------------
// Input projection: X = x @ W_in + b_in   (80000x12 @ 12x256)
// ---------------------------------------------------------------------------
__global__ __launch_bounds__(256) void proj_kernel(
    const float* __restrict__ x, const float* __restrict__ Win,
    const float* __restrict__ bin, float* __restrict__ X) {
  int h = threadIdx.x;
  float w[DIN];
#pragma unroll
  for (int k = 0; k < DIN; k++) w[k] = Win[k * HH + h];
  float bias = bin[h];
  for (int row = blockIdx.x; row < NROWS; row += gridDim.x) {
    float acc = bias;
#pragma unroll
    for (int k = 0; k < DIN; k++) acc = fmaf(x[row * DIN + k], w[k], acc);
    X[(size_t)row * HH + h] = acc;
  }
}

// ---------------------------------------------------------------------------
// LayerNorm over H=256. One row per wave (64 lanes x float4), 4 rows/block.
// ---------------------------------------------------------------------------
__global__ __launch_bounds__(256) void ln_kernel(
    const float* __restrict__ in, float* __restrict__ out,
    const float* __restrict__ g, const float* __restrict__ b) {
  int wave = threadIdx.x >> 6, lane = threadIdx.x & 63;
  int row = blockIdx.x * 4 + wave;
  const float4 v = ((const float4*)(in + (size_t)row * HH))[lane];
  float s = v.x + v.y + v.z + v.w;
  float q = v.x * v.x + v.y * v.y + v.z * v.z + v.w * v.w;
#pragma unroll
  for (int m = 1; m < 64; m <<= 1) { s += __shfl_xor(s, m); q += __shfl_xor(q, m); }
  float mean = s * (1.0f / HH);
  float var = q * (1.0f / HH) - mean * mean;
  float rstd = rsqrtf(var + 1e-5f);
  float4 gg = ((const float4*)g)[lane];
  float4 bb = ((const float4*)b)[lane];
  float4 o;
  o.x = (v.x - mean) * rstd * gg.x + bb.x;
  o.y = (v.y - mean) * rstd * gg.y + bb.y;
  o.z = (v.z - mean) * rstd * gg.z + bb.z;
  o.w = (v.w - mean) * rstd * gg.w + bb.w;
  ((float4*)(out + (size_t)row * HH))[lane] = o;
}

// ---------------------------------------------------------------------------
// Scan pass A: 8 modes per thread (mode split 4-way to keep state in VGPRs).
// lane = h_local*4 + g  -> mode-group g handles n in [g*8, g*8+8).
// Block covers 64 h channels; grid.z covers the 4 h-quarters.
// ---------------------------------------------------------------------------
__global__ __launch_bounds__(256) void scanA_kernel(
    const float* __restrict__ Z, float* __restrict__ S, const float* __restrict__ Wp) {
  int c = blockIdx.x, b = blockIdx.y;
  int h = blockIdx.z * 64 + (threadIdx.x >> 2);
  int g = threadIdx.x & 3;
  const float* wp = Wp + h * (NN * 2) + g * 16;
  float wre[8], wim[8], sre[8], sim[8];
#pragma unroll
  for (int n = 0; n < 8; n++) {
    wre[n] = wp[2 * n]; wim[n] = wp[2 * n + 1];
    sre[n] = 0.0f; sim[n] = 0.0f;
  }
  size_t base = ((size_t)b * LL + (size_t)c * LC) * HH + h;
  float u = Z[base];
  for (int t = 0; t < LC; t++) {
    float un = Z[base + (size_t)(t + 1 < LC ? t + 1 : t) * HH];  // prefetch
#pragma unroll
    for (int n = 0; n < 8; n++) {
      float tr = fmaf(wre[n], sre[n], u);
      tr = fmaf(-wim[n], sim[n], tr);
      float ti = fmaf(wim[n], sre[n], wre[n] * sim[n]);
      sre[n] = tr; sim[n] = ti;
    }
    u = un;
  }
  // S layout: [c][b][h][n][2]; this thread owns 16 consecutive floats.
  float4* sp = (float4*)(S + (((size_t)c * BB + b) * HH + h) * (NN * 2) + g * 16);
#pragma unroll
  for (int q = 0; q < 4; q++) {
    float4 v;
    v.x = sre[2 * q];     v.y = sim[2 * q];
    v.z = sre[2 * q + 1]; v.w = sim[2 * q + 1];
    sp[q] = v;
  }
}

// ---------------------------------------------------------------------------
// Scan pass B: serial scan over chunks per (b,h,n): convert local end-states
// into carry-in states (in place).  carry' = wLc*carry + local ; slot <- carry.
// ---------------------------------------------------------------------------
__global__ __launch_bounds__(256) void combine_kernel(
    float* __restrict__ S, const float* __restrict__ WLc) {
  int tid = blockIdx.x * 256 + threadIdx.x;   // BB*HH*NN = 131072
  int b = tid / (HH * NN);
  int hn = tid % (HH * NN);
  float wre = WLc[2 * hn], wim = WLc[2 * hn + 1];
  float cre = 0.0f, cim = 0.0f;
  for (int c = 0; c < NCH; c++) {
    size_t idx = (((size_t)c * BB + b) * (HH * NN) + hn) * 2;
    float vre = S[idx], vim = S[idx + 1];
    S[idx] = cre; S[idx + 1] = cim;
    float nre2 = fmaf(wre, cre, vre) - wim * cim;
    float nim2 = fmaf(wre, cim, vim) + wim * cre;
    cre = nre2; cim = nim2;
  }
}

// ---------------------------------------------------------------------------
// Scan pass C: replay with carry-in; 8 modes/thread; y = 2Re(sum Ct s) + u*D
// reduced across the 4 mode-group lanes via shuffle; tanh-GELU; write Y.
// NOTE: u*D seeded only in group 0 to avoid 4x counting after the reduce.
// ---------------------------------------------------------------------------
__global__ __launch_bounds__(256) void scanC_kernel(
    const float* __restrict__ Z, const float* __restrict__ S,
    const float* __restrict__ Wp, const float* __restrict__ Ct2,
    const float* __restrict__ Dv, float* __restrict__ Y) {
  int c = blockIdx.x, b = blockIdx.y;
  int h = blockIdx.z * 64 + (threadIdx.x >> 2);
  int g = threadIdx.x & 3;
  const float* wp = Wp + h * (NN * 2) + g * 16;
  const float* cp = Ct2 + h * (NN * 2) + g * 16;
  const float4* sp = (const float4*)(S + (((size_t)c * BB + b) * HH + h) * (NN * 2) + g * 16);
  float wre[8], wim[8], cre[8], cim[8], sre[8], sim[8];
#pragma unroll
  for (int n = 0; n < 8; n++) {
    wre[n] = wp[2 * n]; wim[n] = wp[2 * n + 1];
    cre[n] = cp[2 * n]; cim[n] = cp[2 * n + 1];
  }
#pragma unroll
  for (int q = 0; q < 4; q++) {
    float4 v = sp[q];
    sre[2 * q] = v.x;     sim[2 * q] = v.y;
    sre[2 * q + 1] = v.z; sim[2 * q + 1] = v.w;
  }
  float d = (g == 0) ? Dv[h] : 0.0f;
  size_t base = ((size_t)b * LL + (size_t)c * LC) * HH + h;
  float u = Z[base];
  for (int t = 0; t < LC; t++) {
    float un = Z[base + (size_t)(t + 1 < LC ? t + 1 : t) * HH];  // prefetch
    float acc = u * d;
#pragma unroll
    for (int n = 0; n < 8; n++) {
      float tr = fmaf(wre[n], sre[n], u);
      tr = fmaf(-wim[n], sim[n], tr);
      float ti = fmaf(wim[n], sre[n], wre[n] * sim[n]);
      sre[n] = tr; sim[n] = ti;
      acc = fmaf(cre[n], tr, acc);
      acc = fmaf(-cim[n], ti, acc);
    }
    // reduce across the 4 mode-group lanes (lanes differ in bits 0..1)
    acc += __shfl_xor(acc, 1);
    acc += __shfl_xor(acc, 2);
    // tanh-approx GELU (jax.nn.gelu default)
    float t3 = acc * acc * acc;
    float inner = 0.7978845608028654f * (acc + 0.044715f * t3);
    float y = 0.5f * acc * (1.0f + tanhf(inner));
    if (g == 0) Y[base + (size_t)t * HH] = y;
    u = un;
  }
}

// ---------------------------------------------------------------------------
// GLU FFN: G = Y @ W_glu + b_glu (80000x256 @ 256x512), out = G1*sigmoid(G2)+Z.
// fp32 LDS-tiled GEMM: 64 rows x 128 cols (64 first-half + matching 64 second-
// half columns so GLU pairs live in-register), BK=16, 256 threads, 4x8 micro.
// ---------------------------------------------------------------------------
__global__ __launch_bounds__(256) void gemm_glu_kernel(
    const float* __restrict__ A, const float* __restrict__ W,
    const float* __restrict__ bg, const float* __restrict__ Z,
    float* __restrict__ X) {
  __shared__ float a_s[16][68];   // [k][m]
  __shared__ float b_s[16][128];  // [k][j]; j<64: cols c0+j, j>=64: cols 256+c0+(j-64)
  int r0 = blockIdx.x * 64;
  int c0 = blockIdx.y * 64;
  int t = threadIdx.x;
  int tx = t & 15, ty = t >> 4;
  float acc[4][8];
#pragma unroll
  for (int i = 0; i < 4; i++)
#pragma unroll
    for (int j = 0; j < 8; j++) acc[i][j] = 0.0f;
  int lk = t & 15, lr = t >> 4;
  for (int kt = 0; kt < HH; kt += 16) {
#pragma unroll
    for (int i = 0; i < 4; i++) {
      int m = lr + 16 * i;
      a_s[lk][m] = A[(size_t)(r0 + m) * HH + kt + lk];
    }
#pragma unroll
    for (int i = 0; i < 8; i++) {
      int idx = t + 256 * i;
      int k = idx >> 7, jj = idx & 127;
      int col = (jj < 64) ? (c0 + jj) : (256 + c0 + (jj - 64));
      b_s[k][jj] = W[(kt + k) * 512 + col];
    }
    __syncthreads();
#pragma unroll
    for (int k = 0; k < 16; k++) {
      float4 av = *(const float4*)&a_s[k][ty * 4];
      float4 b0 = *(const float4*)&b_s[k][tx * 4];
      float4 b1 = *(const float4*)&b_s[k][64 + tx * 4];
      float a4[4] = {av.x, av.y, av.z, av.w};
      float bb[8] = {b0.x, b0.y, b0.z, b0.w, b1.x, b1.y, b1.z, b1.w};
#pragma unroll
      for (int i = 0; i < 4; i++)
#pragma unroll
        for (int j = 0; j < 8; j++) acc[i][j] = fmaf(a4[i], bb[j], acc[i][j]);
    }
    __syncthreads();
  }
#pragma unroll
  for (int i = 0; i < 4; i++) {
    int row = r0 + ty * 4 + i;
#pragma unroll
    for (int j = 0; j < 4; j++) {
      int h = c0 + tx * 4 + j;
      float g1 = acc[i][j] + bg[h];
      float g2 = acc[i][4 + j] + bg[256 + h];
      float sig = 1.0f / (1.0f + expf(-g2));
      X[(size_t)row * HH + h] = fmaf(g1, sig, Z[(size_t)row * HH + h]);
    }
  }
}

// ---------------------------------------------------------------------------
extern "C" void kernel_launch(void* const* d_in, const int* in_sizes, int n_in,
                              void* d_out, int out_size, void* d_ws, size_t ws_size,
                              hipStream_t stream) {
  const float* x      = (const float*)d_in[0];
  const float* Win    = (const float*)d_in[1];
  const float* bin    = (const float*)d_in[2];
  const float* ln_g   = (const float*)d_in[3];
  const float* ln_b   = (const float*)d_in[4];
  const float* log_dt = (const float*)d_in[5];
  const float* logA   = (const float*)d_in[6];
  const float* A_im   = (const float*)d_in[7];
  const float* Cp     = (const float*)d_in[8];
  const float* Dv     = (const float*)d_in[9];
  const float* Wglu   = (const float*)d_in[10];
  const float* bglu   = (const float*)d_in[11];
  const float* fn_g   = (const float*)d_in[12];
  const float* fn_b   = (const float*)d_in[13];
  float* out = (float*)d_out;
  float* ws = (float*)d_ws;

  float* X   = ws;                               // 20,480,000 floats
  float* Z   = X + (size_t)NROWS * HH;           // 20,480,000 floats
  float* S   = Z + (size_t)NROWS * HH;           // 10,485,760 floats
  float* Wp  = S + SSIZE;                        // 65,536 floats
  float* Ct2 = Wp + (size_t)NLAYER * PSTRIDE;    // 65,536 floats
  float* WLc = Ct2 + (size_t)NLAYER * PSTRIDE;   // 65,536 floats
  float* Y   = out;                              // reuse d_out as activation scratch

  param_kernel<<<(NLAYER * HH * NN) / 256, 256, 0, stream>>>(log_dt, logA, A_im, Cp, Wp, Ct2, WLc);
  proj_kernel<<<2048, 256, 0, stream>>>(x, Win, bin, X);

  for (int l = 0; l < NLAYER; l++) {
    ln_kernel<<<NROWS / 4, 256, 0, stream>>>(X, Z, ln_g + l * HH, ln_b + l * HH);
    scanA_kernel<<<dim3(NCH, BB, 4), 256, 0, stream>>>(Z, S, Wp + (size_t)l * PSTRIDE);
    combine_kernel<<<(BB * HH * NN) / 256, 256, 0, stream>>>(S, WLc + (size_t)l * PSTRIDE);
    scanC_kernel<<<dim3(NCH, BB, 4), 256, 0, stream>>>(Z, S, Wp + (size_t)l * PSTRIDE,
                                                       Ct2 + (size_t)l * PSTRIDE, Dv + l * HH, Y);
    gemm_glu_kernel<<<dim3(NROWS / 64, 4), 256, 0, stream>>>(
        Y, Wglu + (size_t)l * HH * 2 * HH, bglu + l * 2 * HH, Z, X);
  }
  ln_kernel<<<NROWS / 4, 256, 0, stream>>>(X, out, fn_g, fn_b);
}

// Round 3
// 1736.276 us; speedup vs baseline: 4.3384x; 1.4353x over previous
//
#include <hip/hip_runtime.h>
#include <hip/hip_bf16.h>
#include <math.h>

// Problem constants
#define BB 16
#define LL 5000
#define DIN 12
#define HH 256
#define NN 32
#define NLAYER 4
#define LC 125              // chunk length
#define NCH 40              // number of chunks (40*125 = 5000)
#define NROWS (BB*LL)       // 80000 rows of H=256

#define SSIZE ((size_t)NCH*BB*HH*NN*2)   // chunk-state buffer (complex) = 10,485,760 floats
#define PSTRIDE (HH*NN*2)                // per-layer param stride = 16384 floats

typedef __attribute__((ext_vector_type(8))) __bf16 bf16x8;
typedef __attribute__((ext_vector_type(4))) float f32x4;

// ---------------------------------------------------------------------------
// Per-layer SSM parameter precompute: w = exp(dt*A), Ct2 = 2*C*(w-1)/A, wLc = w^LC
// ---------------------------------------------------------------------------
__global__ __launch_bounds__(256) void param_kernel(
    const float* __restrict__ log_dt, const float* __restrict__ logA_re,
    const float* __restrict__ A_im, const float* __restrict__ Cp,
    float* __restrict__ Wp, float* __restrict__ Ct2, float* __restrict__ WLc) {
  int gid = blockIdx.x * 256 + threadIdx.x;       // NLAYER*HH*NN = 32768
  if (gid >= NLAYER * HH * NN) return;
  int l = gid / (HH * NN);
  int hn = gid % (HH * NN);
  int h = hn / NN;
  float dt = expf(log_dt[l * HH + h]);
  float Are = -expf(logA_re[gid]);
  float Aim = A_im[gid];
  float are = Are * dt, aim = Aim * dt;
  float e = expf(are);
  float wre = e * cosf(aim), wim = e * sinf(aim);
  float Crev = Cp[2 * gid], Cimv = Cp[2 * gid + 1];
  float nre = wre - 1.0f, nim = wim;
  float tre = Crev * nre - Cimv * nim;
  float tim = Crev * nim + Cimv * nre;
  float inv = 1.0f / (Are * Are + Aim * Aim);
  float ctre = (tre * Are + tim * Aim) * inv;     // t * conj(A) / |A|^2
  float ctim = (tim * Are - tre * Aim) * inv;
  Wp[2 * gid] = wre; Wp[2 * gid + 1] = wim;
  Ct2[2 * gid] = 2.0f * ctre; Ct2[2 * gid + 1] = 2.0f * ctim;
  float eL = expf(are * (float)LC);
  float ang = aim * (float)LC;
  WLc[2 * gid] = eL * cosf(ang);
  WLc[2 * gid + 1] = eL * sinf(ang);
}

// ---------------------------------------------------------------------------
// W_glu transpose+cast: Wt[l][col(512)][k(256)] bf16. Reads coalesced over col.
// ---------------------------------------------------------------------------
__global__ __launch_bounds__(256) void wt_kernel(
    const float* __restrict__ W, __hip_bfloat16* __restrict__ Wt) {
  int gid = blockIdx.x * 256 + threadIdx.x;   // NLAYER*512 = 2048
  int l = gid >> 9, col = gid & 511;
  const float* w = W + (size_t)l * HH * 512 + col;
  __hip_bfloat16* o = Wt + (size_t)gid * HH;
  for (int k = 0; k < HH; k++) o[k] = __float2bfloat16(w[(size_t)k * 512]);
}

// ---------------------------------------------------------------------------
// Input projection: X = x @ W_in + b_in   (80000x12 @ 12x256)
// ---------------------------------------------------------------------------
__global__ __launch_bounds__(256) void proj_kernel(
    const float* __restrict__ x, const float* __restrict__ Win,
    const float* __restrict__ bin, float* __restrict__ X) {
  int h = threadIdx.x;
  float w[DIN];
#pragma unroll
  for (int k = 0; k < DIN; k++) w[k] = Win[k * HH + h];
  float bias = bin[h];
  for (int row = blockIdx.x; row < NROWS; row += gridDim.x) {
    float acc = bias;
#pragma unroll
    for (int k = 0; k < DIN; k++) acc = fmaf(x[row * DIN + k], w[k], acc);
    X[(size_t)row * HH + h] = acc;
  }
}

// ---------------------------------------------------------------------------
// LayerNorm over H=256. One row per wave (64 lanes x float4), 4 rows/block.
// ---------------------------------------------------------------------------
__global__ __launch_bounds__(256) void ln_kernel(
    const float* __restrict__ in, float* __restrict__ out,
    const float* __restrict__ g, const float* __restrict__ b) {
  int wave = threadIdx.x >> 6, lane = threadIdx.x & 63;
  int row = blockIdx.x * 4 + wave;
  const float4 v = ((const float4*)(in + (size_t)row * HH))[lane];
  float s = v.x + v.y + v.z + v.w;
  float q = v.x * v.x + v.y * v.y + v.z * v.z + v.w * v.w;
#pragma unroll
  for (int m = 1; m < 64; m <<= 1) { s += __shfl_xor(s, m); q += __shfl_xor(q, m); }
  float mean = s * (1.0f / HH);
  float var = q * (1.0f / HH) - mean * mean;
  float rstd = rsqrtf(var + 1e-5f);
  float4 gg = ((const float4*)g)[lane];
  float4 bb = ((const float4*)b)[lane];
  float4 o;
  o.x = (v.x - mean) * rstd * gg.x + bb.x;
  o.y = (v.y - mean) * rstd * gg.y + bb.y;
  o.z = (v.z - mean) * rstd * gg.z + bb.z;
  o.w = (v.w - mean) * rstd * gg.w + bb.w;
  ((float4*)(out + (size_t)row * HH))[lane] = o;
}

// ---------------------------------------------------------------------------
// Scan pass A: 8 modes per thread (mode split 4-way to keep state in VGPRs).
// ---------------------------------------------------------------------------
__global__ __launch_bounds__(256) void scanA_kernel(
    const float* __restrict__ Z, float* __restrict__ S, const float* __restrict__ Wp) {
  int c = blockIdx.x, b = blockIdx.y;
  int h = blockIdx.z * 64 + (threadIdx.x >> 2);
  int g = threadIdx.x & 3;
  const float* wp = Wp + h * (NN * 2) + g * 16;
  float wre[8], wim[8], sre[8], sim[8];
#pragma unroll
  for (int n = 0; n < 8; n++) {
    wre[n] = wp[2 * n]; wim[n] = wp[2 * n + 1];
    sre[n] = 0.0f; sim[n] = 0.0f;
  }
  size_t base = ((size_t)b * LL + (size_t)c * LC) * HH + h;
  float u = Z[base];
  for (int t = 0; t < LC; t++) {
    float un = Z[base + (size_t)(t + 1 < LC ? t + 1 : t) * HH];  // prefetch
#pragma unroll
    for (int n = 0; n < 8; n++) {
      float tr = fmaf(wre[n], sre[n], u);
      tr = fmaf(-wim[n], sim[n], tr);
      float ti = fmaf(wim[n], sre[n], wre[n] * sim[n]);
      sre[n] = tr; sim[n] = ti;
    }
    u = un;
  }
  float4* sp = (float4*)(S + (((size_t)c * BB + b) * HH + h) * (NN * 2) + g * 16);
#pragma unroll
  for (int q = 0; q < 4; q++) {
    float4 v;
    v.x = sre[2 * q];     v.y = sim[2 * q];
    v.z = sre[2 * q + 1]; v.w = sim[2 * q + 1];
    sp[q] = v;
  }
}

// ---------------------------------------------------------------------------
// Scan pass B: serial scan over chunks per (b,h,n) (in place).
// ---------------------------------------------------------------------------
__global__ __launch_bounds__(256) void combine_kernel(
    float* __restrict__ S, const float* __restrict__ WLc) {
  int tid = blockIdx.x * 256 + threadIdx.x;   // BB*HH*NN = 131072
  int b = tid / (HH * NN);
  int hn = tid % (HH * NN);
  float wre = WLc[2 * hn], wim = WLc[2 * hn + 1];
  float cre = 0.0f, cim = 0.0f;
  for (int c = 0; c < NCH; c++) {
    size_t idx = (((size_t)c * BB + b) * (HH * NN) + hn) * 2;
    float vre = S[idx], vim = S[idx + 1];
    S[idx] = cre; S[idx + 1] = cim;
    float nre2 = fmaf(wre, cre, vre) - wim * cim;
    float nim2 = fmaf(wre, cim, vim) + wim * cre;
    cre = nre2; cim = nim2;
  }
}

// ---------------------------------------------------------------------------
// Scan pass C: replay with carry-in; y = 2Re(sum Ct s) + u*D; tanh-GELU;
// write Y in bf16 (feeds the MFMA GEMM).
// ---------------------------------------------------------------------------
__global__ __launch_bounds__(256) void scanC_kernel(
    const float* __restrict__ Z, const float* __restrict__ S,
    const float* __restrict__ Wp, const float* __restrict__ Ct2,
    const float* __restrict__ Dv, __hip_bfloat16* __restrict__ Y) {
  int c = blockIdx.x, b = blockIdx.y;
  int h = blockIdx.z * 64 + (threadIdx.x >> 2);
  int g = threadIdx.x & 3;
  const float* wp = Wp + h * (NN * 2) + g * 16;
  const float* cp = Ct2 + h * (NN * 2) + g * 16;
  const float4* sp = (const float4*)(S + (((size_t)c * BB + b) * HH + h) * (NN * 2) + g * 16);
  float wre[8], wim[8], cre[8], cim[8], sre[8], sim[8];
#pragma unroll
  for (int n = 0; n < 8; n++) {
    wre[n] = wp[2 * n]; wim[n] = wp[2 * n + 1];
    cre[n] = cp[2 * n]; cim[n] = cp[2 * n + 1];
  }
#pragma unroll
  for (int q = 0; q < 4; q++) {
    float4 v = sp[q];
    sre[2 * q] = v.x;     sim[2 * q] = v.y;
    sre[2 * q + 1] = v.z; sim[2 * q + 1] = v.w;
  }
  float d = (g == 0) ? Dv[h] : 0.0f;
  size_t base = ((size_t)b * LL + (size_t)c * LC) * HH + h;
  float u = Z[base];
  for (int t = 0; t < LC; t++) {
    float un = Z[base + (size_t)(t + 1 < LC ? t + 1 : t) * HH];  // prefetch
    float acc = u * d;
#pragma unroll
    for (int n = 0; n < 8; n++) {
      float tr = fmaf(wre[n], sre[n], u);
      tr = fmaf(-wim[n], sim[n], tr);
      float ti = fmaf(wim[n], sre[n], wre[n] * sim[n]);
      sre[n] = tr; sim[n] = ti;
      acc = fmaf(cre[n], tr, acc);
      acc = fmaf(-cim[n], ti, acc);
    }
    acc += __shfl_xor(acc, 1);
    acc += __shfl_xor(acc, 2);
    float t3 = acc * acc * acc;
    float inner = 0.7978845608028654f * (acc + 0.044715f * t3);
    float y = 0.5f * acc * (1.0f + tanhf(inner));
    if (g == 0) Y[base + (size_t)t * HH] = __float2bfloat16(y);
    u = un;
  }
}

// ---------------------------------------------------------------------------
// GLU FFN via bf16 MFMA: G = Y @ W_glu + b_glu, out = G1*sigmoid(G2) + Z.
// Block tile: 128 rows x 64 GLU pairs (=128 W cols: 64 first-half + 64
// second-half). 4 waves; wave (rh,ch) owns rows rh*64..+64, pairs ch*32..+32
// with both G1 (j=0,1) and G2 (j=2,3) tiles so GLU is register-local.
// BK=64, LDS row stride 72 bf16 (2-way bank alias = free).
// ---------------------------------------------------------------------------
__global__ __launch_bounds__(256) void gemm_glu_mfma(
    const __hip_bfloat16* __restrict__ Y, const __hip_bfloat16* __restrict__ Wt,
    const float* __restrict__ bg, const float* __restrict__ Z,
    float* __restrict__ X) {
  __shared__ __bf16 As[128 * 72];
  __shared__ __bf16 Bs[128 * 72];
  int t = threadIdx.x;
  int r0 = blockIdx.x * 128, c0 = blockIdx.y * 64;
  int w = t >> 6, lane = t & 63;
  int lr = lane & 15, quad = lane >> 4;
  int rh = w & 1, ch = w >> 1;
  f32x4 acc[4][4];
#pragma unroll
  for (int i = 0; i < 4; i++)
#pragma unroll
    for (int j = 0; j < 4; j++) acc[i][j] = (f32x4)(0.0f);

  int jb[4] = {ch * 32, ch * 32 + 16, 64 + ch * 32, 80 + ch * 32};

  for (int kt = 0; kt < HH; kt += 64) {
#pragma unroll
    for (int i = 0; i < 4; i++) {
      int idx = t + 256 * i;
      int m = idx >> 3, q = idx & 7;
      uint4 v = *(const uint4*)(Y + (size_t)(r0 + m) * HH + kt + q * 8);
      *(uint4*)&As[m * 72 + q * 8] = v;
    }
#pragma unroll
    for (int i = 0; i < 4; i++) {
      int idx = t + 256 * i;
      int jj = idx >> 3, q = idx & 7;
      int col = (jj < 64) ? (c0 + jj) : (192 + c0 + jj);
      uint4 v = *(const uint4*)(Wt + (size_t)col * HH + kt + q * 8);
      *(uint4*)&Bs[jj * 72 + q * 8] = v;
    }
    __syncthreads();
#pragma unroll
    for (int ks = 0; ks < 2; ks++) {
      bf16x8 af[4], bf[4];
#pragma unroll
      for (int i = 0; i < 4; i++)
        af[i] = *(const bf16x8*)&As[(rh * 64 + i * 16 + lr) * 72 + ks * 32 + quad * 8];
#pragma unroll
      for (int j = 0; j < 4; j++)
        bf[j] = *(const bf16x8*)&Bs[(jb[j] + lr) * 72 + ks * 32 + quad * 8];
#pragma unroll
      for (int i = 0; i < 4; i++)
#pragma unroll
        for (int j = 0; j < 4; j++)
          acc[i][j] = __builtin_amdgcn_mfma_f32_16x16x32_bf16(af[i], bf[j], acc[i][j], 0, 0, 0);
    }
    __syncthreads();
  }

  // Epilogue: C/D layout col = lane&15, row = quad*4 + reg
#pragma unroll
  for (int i = 0; i < 4; i++) {
#pragma unroll
    for (int r = 0; r < 4; r++) {
      int row = r0 + rh * 64 + i * 16 + quad * 4 + r;
#pragma unroll
      for (int jp = 0; jp < 2; jp++) {
        int h = c0 + ch * 32 + jp * 16 + lr;
        float g1 = acc[i][jp][r] + bg[h];
        float g2 = acc[i][jp + 2][r] + bg[256 + h];
        float sig = 1.0f / (1.0f + expf(-g2));
        X[(size_t)row * HH + h] = fmaf(g1, sig, Z[(size_t)row * HH + h]);
      }
    }
  }
}

// ---------------------------------------------------------------------------
extern "C" void kernel_launch(void* const* d_in, const int* in_sizes, int n_in,
                              void* d_out, int out_size, void* d_ws, size_t ws_size,
                              hipStream_t stream) {
  const float* x      = (const float*)d_in[0];
  const float* Win    = (const float*)d_in[1];
  const float* bin    = (const float*)d_in[2];
  const float* ln_g   = (const float*)d_in[3];
  const float* ln_b   = (const float*)d_in[4];
  const float* log_dt = (const float*)d_in[5];
  const float* logA   = (const float*)d_in[6];
  const float* A_im   = (const float*)d_in[7];
  const float* Cp     = (const float*)d_in[8];
  const float* Dv     = (const float*)d_in[9];
  const float* Wglu   = (const float*)d_in[10];
  const float* bglu   = (const float*)d_in[11];
  const float* fn_g   = (const float*)d_in[12];
  const float* fn_b   = (const float*)d_in[13];
  float* out = (float*)d_out;
  float* ws = (float*)d_ws;

  float* X   = ws;                               // 20,480,000 floats
  float* Z   = X + (size_t)NROWS * HH;           // 20,480,000 floats
  float* S   = Z + (size_t)NROWS * HH;           // 10,485,760 floats
  float* Wp  = S + SSIZE;                        // 65,536 floats
  float* Ct2 = Wp + (size_t)NLAYER * PSTRIDE;    // 65,536 floats
  float* WLc = Ct2 + (size_t)NLAYER * PSTRIDE;   // 65,536 floats
  __hip_bfloat16* Wt = (__hip_bfloat16*)(WLc + (size_t)NLAYER * PSTRIDE);  // 524,288 bf16
  __hip_bfloat16* Y  = (__hip_bfloat16*)d_out;   // reuse d_out as bf16 activation scratch

  param_kernel<<<(NLAYER * HH * NN) / 256, 256, 0, stream>>>(log_dt, logA, A_im, Cp, Wp, Ct2, WLc);
  wt_kernel<<<(NLAYER * 512) / 256, 256, 0, stream>>>(Wglu, Wt);
  proj_kernel<<<2048, 256, 0, stream>>>(x, Win, bin, X);

  for (int l = 0; l < NLAYER; l++) {
    ln_kernel<<<NROWS / 4, 256, 0, stream>>>(X, Z, ln_g + l * HH, ln_b + l * HH);
    scanA_kernel<<<dim3(NCH, BB, 4), 256, 0, stream>>>(Z, S, Wp + (size_t)l * PSTRIDE);
    combine_kernel<<<(BB * HH * NN) / 256, 256, 0, stream>>>(S, WLc + (size_t)l * PSTRIDE);
    scanC_kernel<<<dim3(NCH, BB, 4), 256, 0, stream>>>(Z, S, Wp + (size_t)l * PSTRIDE,
                                                       Ct2 + (size_t)l * PSTRIDE, Dv + l * HH, Y);
    gemm_glu_mfma<<<dim3(NROWS / 128, 4), 256, 0, stream>>>(
        Y, Wt + (size_t)l * 512 * HH, bglu + l * 2 * HH, Z, X);
  }
  ln_kernel<<<NROWS / 4, 256, 0, stream>>>(X, out, fn_g, fn_b);
}

// Round 4
// 1540.278 us; speedup vs baseline: 4.8905x; 1.1272x over previous
//
#include <hip/hip_runtime.h>
#include <hip/hip_bf16.h>
#include <math.h>

// Problem constants
#define BB 16
#define LL 5000
#define DIN 12
#define HH 256
#define NN 32
#define NLAYER 4
#define LC 125              // chunk length
#define NCH 40              // number of chunks (40*125 = 5000)
#define NROWS (BB*LL)       // 80000 rows of H=256

#define SSIZE ((size_t)NCH*BB*HH*NN*2)   // chunk-state buffer (complex) = 10,485,760 floats
#define PSTRIDE (HH*NN*2)                // per-layer param stride = 16384 floats

typedef __attribute__((ext_vector_type(8))) __bf16 bf16x8;
typedef __attribute__((ext_vector_type(4))) float f32x4;

// fast tanh-GELU: 0.5*a*(1+tanh(0.797885*(a+0.044715*a^3))) == a*sigmoid(2*inner)
__device__ __forceinline__ float fast_gelu(float a) {
  float z = fmaf(0.0713548163f * a, a * a, 1.5957691216f * a);  // 2*inner
  float e = __expf(-z);
  return a * __builtin_amdgcn_rcpf(1.0f + e);
}

// ---------------------------------------------------------------------------
// Per-layer SSM parameter precompute: w = exp(dt*A), Ct2 = 2*C*(w-1)/A, wLc = w^LC
// ---------------------------------------------------------------------------
__global__ __launch_bounds__(256) void param_kernel(
    const float* __restrict__ log_dt, const float* __restrict__ logA_re,
    const float* __restrict__ A_im, const float* __restrict__ Cp,
    float* __restrict__ Wp, float* __restrict__ Ct2, float* __restrict__ WLc) {
  int gid = blockIdx.x * 256 + threadIdx.x;       // NLAYER*HH*NN = 32768
  if (gid >= NLAYER * HH * NN) return;
  int l = gid / (HH * NN);
  int hn = gid % (HH * NN);
  int h = hn / NN;
  float dt = expf(log_dt[l * HH + h]);
  float Are = -expf(logA_re[gid]);
  float Aim = A_im[gid];
  float are = Are * dt, aim = Aim * dt;
  float e = expf(are);
  float wre = e * cosf(aim), wim = e * sinf(aim);
  float Crev = Cp[2 * gid], Cimv = Cp[2 * gid + 1];
  float nre = wre - 1.0f, nim = wim;
  float tre = Crev * nre - Cimv * nim;
  float tim = Crev * nim + Cimv * nre;
  float inv = 1.0f / (Are * Are + Aim * Aim);
  float ctre = (tre * Are + tim * Aim) * inv;     // t * conj(A) / |A|^2
  float ctim = (tim * Are - tre * Aim) * inv;
  Wp[2 * gid] = wre; Wp[2 * gid + 1] = wim;
  Ct2[2 * gid] = 2.0f * ctre; Ct2[2 * gid + 1] = 2.0f * ctim;
  float eL = expf(are * (float)LC);
  float ang = aim * (float)LC;
  WLc[2 * gid] = eL * cosf(ang);
  WLc[2 * gid + 1] = eL * sinf(ang);
}

// ---------------------------------------------------------------------------
// W_glu transpose+cast: Wt[l][col(512)][k(256)] bf16. Reads coalesced over col.
// ---------------------------------------------------------------------------
__global__ __launch_bounds__(256) void wt_kernel(
    const float* __restrict__ W, __hip_bfloat16* __restrict__ Wt) {
  int gid = blockIdx.x * 256 + threadIdx.x;   // NLAYER*512 = 2048
  int l = gid >> 9, col = gid & 511;
  const float* w = W + (size_t)l * HH * 512 + col;
  __hip_bfloat16* o = Wt + (size_t)gid * HH;
  for (int k = 0; k < HH; k++) o[k] = __float2bfloat16(w[(size_t)k * 512]);
}

// ---------------------------------------------------------------------------
// Input projection: X = x @ W_in + b_in   (80000x12 @ 12x256)
// ---------------------------------------------------------------------------
__global__ __launch_bounds__(256) void proj_kernel(
    const float* __restrict__ x, const float* __restrict__ Win,
    const float* __restrict__ bin, float* __restrict__ X) {
  int h = threadIdx.x;
  float w[DIN];
#pragma unroll
  for (int k = 0; k < DIN; k++) w[k] = Win[k * HH + h];
  float bias = bin[h];
  for (int row = blockIdx.x; row < NROWS; row += gridDim.x) {
    float acc = bias;
#pragma unroll
    for (int k = 0; k < DIN; k++) acc = fmaf(x[row * DIN + k], w[k], acc);
    X[(size_t)row * HH + h] = acc;
  }
}

// ---------------------------------------------------------------------------
// LayerNorm over H=256. One row per wave (64 lanes x float4), 4 rows/block.
// ---------------------------------------------------------------------------
__global__ __launch_bounds__(256) void ln_kernel(
    const float* __restrict__ in, float* __restrict__ out,
    const float* __restrict__ g, const float* __restrict__ b) {
  int wave = threadIdx.x >> 6, lane = threadIdx.x & 63;
  int row = blockIdx.x * 4 + wave;
  const float4 v = ((const float4*)(in + (size_t)row * HH))[lane];
  float s = v.x + v.y + v.z + v.w;
  float q = v.x * v.x + v.y * v.y + v.z * v.z + v.w * v.w;
#pragma unroll
  for (int m = 1; m < 64; m <<= 1) { s += __shfl_xor(s, m); q += __shfl_xor(q, m); }
  float mean = s * (1.0f / HH);
  float var = q * (1.0f / HH) - mean * mean;
  float rstd = rsqrtf(var + 1e-5f);
  float4 gg = ((const float4*)g)[lane];
  float4 bb = ((const float4*)b)[lane];
  float4 o;
  o.x = (v.x - mean) * rstd * gg.x + bb.x;
  o.y = (v.y - mean) * rstd * gg.y + bb.y;
  o.z = (v.z - mean) * rstd * gg.z + bb.z;
  o.w = (v.w - mean) * rstd * gg.w + bb.w;
  ((float4*)(out + (size_t)row * HH))[lane] = o;
}

// ---------------------------------------------------------------------------
// Scan pass A: 8 modes per thread (mode split 4-way to keep state in VGPRs).
// Steady-state loop has no bounds-check; last step peeled.
// ---------------------------------------------------------------------------
__global__ __launch_bounds__(256) void scanA_kernel(
    const float* __restrict__ Z, float* __restrict__ S, const float* __restrict__ Wp) {
  int c = blockIdx.x, b = blockIdx.y;
  int h = blockIdx.z * 64 + (threadIdx.x >> 2);
  int g = threadIdx.x & 3;
  const float* wp = Wp + h * (NN * 2) + g * 16;
  float wre[8], wim[8], sre[8], sim[8];
#pragma unroll
  for (int n = 0; n < 8; n++) {
    wre[n] = wp[2 * n]; wim[n] = wp[2 * n + 1];
    sre[n] = 0.0f; sim[n] = 0.0f;
  }
  const float* zp = Z + ((size_t)b * LL + (size_t)c * LC) * HH + h;
  float u = *zp;
  for (int t = 0; t < LC - 1; t++) {
    zp += HH;
    float un = *zp;
#pragma unroll
    for (int n = 0; n < 8; n++) {
      float tr = fmaf(wre[n], sre[n], u);
      tr = fmaf(-wim[n], sim[n], tr);
      float ti = fmaf(wim[n], sre[n], wre[n] * sim[n]);
      sre[n] = tr; sim[n] = ti;
    }
    u = un;
  }
#pragma unroll
  for (int n = 0; n < 8; n++) {
    float tr = fmaf(wre[n], sre[n], u);
    tr = fmaf(-wim[n], sim[n], tr);
    float ti = fmaf(wim[n], sre[n], wre[n] * sim[n]);
    sre[n] = tr; sim[n] = ti;
  }
  float4* sp = (float4*)(S + (((size_t)c * BB + b) * HH + h) * (NN * 2) + g * 16);
#pragma unroll
  for (int q = 0; q < 4; q++) {
    float4 v;
    v.x = sre[2 * q];     v.y = sim[2 * q];
    v.z = sre[2 * q + 1]; v.w = sim[2 * q + 1];
    sp[q] = v;
  }
}

// ---------------------------------------------------------------------------
// Scan pass B: serial scan over chunks per (b,h,n) (in place).
// ---------------------------------------------------------------------------
__global__ __launch_bounds__(256) void combine_kernel(
    float* __restrict__ S, const float* __restrict__ WLc) {
  int tid = blockIdx.x * 256 + threadIdx.x;   // BB*HH*NN = 131072
  int b = tid / (HH * NN);
  int hn = tid % (HH * NN);
  float wre = WLc[2 * hn], wim = WLc[2 * hn + 1];
  float cre = 0.0f, cim = 0.0f;
  for (int c = 0; c < NCH; c++) {
    size_t idx = (((size_t)c * BB + b) * (HH * NN) + hn) * 2;
    float vre = S[idx], vim = S[idx + 1];
    S[idx] = cre; S[idx + 1] = cim;
    float nre2 = fmaf(wre, cre, vre) - wim * cim;
    float nim2 = fmaf(wre, cim, vim) + wim * cre;
    cre = nre2; cim = nim2;
  }
}

// ---------------------------------------------------------------------------
// Scan pass C: replay with carry-in; y = 2Re(sum Ct s) + u*D; fast GELU;
// write Y in bf16 (feeds the MFMA GEMM). Last step peeled.
// ---------------------------------------------------------------------------
__global__ __launch_bounds__(256) void scanC_kernel(
    const float* __restrict__ Z, const float* __restrict__ S,
    const float* __restrict__ Wp, const float* __restrict__ Ct2,
    const float* __restrict__ Dv, __hip_bfloat16* __restrict__ Y) {
  int c = blockIdx.x, b = blockIdx.y;
  int h = blockIdx.z * 64 + (threadIdx.x >> 2);
  int g = threadIdx.x & 3;
  const float* wp = Wp + h * (NN * 2) + g * 16;
  const float* cp = Ct2 + h * (NN * 2) + g * 16;
  const float4* sp = (const float4*)(S + (((size_t)c * BB + b) * HH + h) * (NN * 2) + g * 16);
  float wre[8], wim[8], cre[8], cim[8], sre[8], sim[8];
#pragma unroll
  for (int n = 0; n < 8; n++) {
    wre[n] = wp[2 * n]; wim[n] = wp[2 * n + 1];
    cre[n] = cp[2 * n]; cim[n] = cp[2 * n + 1];
  }
#pragma unroll
  for (int q = 0; q < 4; q++) {
    float4 v = sp[q];
    sre[2 * q] = v.x;     sim[2 * q] = v.y;
    sre[2 * q + 1] = v.z; sim[2 * q + 1] = v.w;
  }
  float d = (g == 0) ? Dv[h] : 0.0f;
  size_t base = ((size_t)b * LL + (size_t)c * LC) * HH + h;
  const float* zp = Z + base;
  __hip_bfloat16* yp = Y + base;
  float u = *zp;
  for (int t = 0; t < LC - 1; t++) {
    zp += HH;
    float un = *zp;
    float acc = u * d;
#pragma unroll
    for (int n = 0; n < 8; n++) {
      float tr = fmaf(wre[n], sre[n], u);
      tr = fmaf(-wim[n], sim[n], tr);
      float ti = fmaf(wim[n], sre[n], wre[n] * sim[n]);
      sre[n] = tr; sim[n] = ti;
      acc = fmaf(cre[n], tr, acc);
      acc = fmaf(-cim[n], ti, acc);
    }
    acc += __shfl_xor(acc, 1);
    acc += __shfl_xor(acc, 2);
    if (g == 0) *yp = __float2bfloat16(fast_gelu(acc));
    yp += HH;
    u = un;
  }
  {
    float acc = u * d;
#pragma unroll
    for (int n = 0; n < 8; n++) {
      float tr = fmaf(wre[n], sre[n], u);
      tr = fmaf(-wim[n], sim[n], tr);
      float ti = fmaf(wim[n], sre[n], wre[n] * sim[n]);
      acc = fmaf(cre[n], tr, acc);
      acc = fmaf(-cim[n], ti, acc);
    }
    acc += __shfl_xor(acc, 1);
    acc += __shfl_xor(acc, 2);
    if (g == 0) *yp = __float2bfloat16(fast_gelu(acc));
  }
}

// ---------------------------------------------------------------------------
// GLU FFN via bf16 MFMA: G = Y @ W_glu + b_glu, out = G1*sigmoid(G2) + Z.
// Block tile: 128 rows x 64 GLU pairs. BK=64, LDS row stride 72 bf16.
// ---------------------------------------------------------------------------
__global__ __launch_bounds__(256) void gemm_glu_mfma(
    const __hip_bfloat16* __restrict__ Y, const __hip_bfloat16* __restrict__ Wt,
    const float* __restrict__ bg, const float* __restrict__ Z,
    float* __restrict__ X) {
  __shared__ __bf16 As[128 * 72];
  __shared__ __bf16 Bs[128 * 72];
  int t = threadIdx.x;
  int r0 = blockIdx.x * 128, c0 = blockIdx.y * 64;
  int w = t >> 6, lane = t & 63;
  int lr = lane & 15, quad = lane >> 4;
  int rh = w & 1, ch = w >> 1;
  f32x4 acc[4][4];
#pragma unroll
  for (int i = 0; i < 4; i++)
#pragma unroll
    for (int j = 0; j < 4; j++) acc[i][j] = (f32x4)(0.0f);

  int jb[4] = {ch * 32, ch * 32 + 16, 64 + ch * 32, 80 + ch * 32};

  for (int kt = 0; kt < HH; kt += 64) {
#pragma unroll
    for (int i = 0; i < 4; i++) {
      int idx = t + 256 * i;
      int m = idx >> 3, q = idx & 7;
      uint4 v = *(const uint4*)(Y + (size_t)(r0 + m) * HH + kt + q * 8);
      *(uint4*)&As[m * 72 + q * 8] = v;
    }
#pragma unroll
    for (int i = 0; i < 4; i++) {
      int idx = t + 256 * i;
      int jj = idx >> 3, q = idx & 7;
      int col = (jj < 64) ? (c0 + jj) : (192 + c0 + jj);
      uint4 v = *(const uint4*)(Wt + (size_t)col * HH + kt + q * 8);
      *(uint4*)&Bs[jj * 72 + q * 8] = v;
    }
    __syncthreads();
#pragma unroll
    for (int ks = 0; ks < 2; ks++) {
      bf16x8 af[4], bf[4];
#pragma unroll
      for (int i = 0; i < 4; i++)
        af[i] = *(const bf16x8*)&As[(rh * 64 + i * 16 + lr) * 72 + ks * 32 + quad * 8];
#pragma unroll
      for (int j = 0; j < 4; j++)
        bf[j] = *(const bf16x8*)&Bs[(jb[j] + lr) * 72 + ks * 32 + quad * 8];
#pragma unroll
      for (int i = 0; i < 4; i++)
#pragma unroll
        for (int j = 0; j < 4; j++)
          acc[i][j] = __builtin_amdgcn_mfma_f32_16x16x32_bf16(af[i], bf[j], acc[i][j], 0, 0, 0);
    }
    __syncthreads();
  }

  // Epilogue: C/D layout col = lane&15, row = quad*4 + reg
#pragma unroll
  for (int i = 0; i < 4; i++) {
#pragma unroll
    for (int r = 0; r < 4; r++) {
      int row = r0 + rh * 64 + i * 16 + quad * 4 + r;
#pragma unroll
      for (int jp = 0; jp < 2; jp++) {
        int h = c0 + ch * 32 + jp * 16 + lr;
        float g1 = acc[i][jp][r] + bg[h];
        float g2 = acc[i][jp + 2][r] + bg[256 + h];
        float sig = __builtin_amdgcn_rcpf(1.0f + __expf(-g2));
        X[(size_t)row * HH + h] = fmaf(g1, sig, Z[(size_t)row * HH + h]);
      }
    }
  }
}

// ---------------------------------------------------------------------------
extern "C" void kernel_launch(void* const* d_in, const int* in_sizes, int n_in,
                              void* d_out, int out_size, void* d_ws, size_t ws_size,
                              hipStream_t stream) {
  const float* x      = (const float*)d_in[0];
  const float* Win    = (const float*)d_in[1];
  const float* bin    = (const float*)d_in[2];
  const float* ln_g   = (const float*)d_in[3];
  const float* ln_b   = (const float*)d_in[4];
  const float* log_dt = (const float*)d_in[5];
  const float* logA   = (const float*)d_in[6];
  const float* A_im   = (const float*)d_in[7];
  const float* Cp     = (const float*)d_in[8];
  const float* Dv     = (const float*)d_in[9];
  const float* Wglu   = (const float*)d_in[10];
  const float* bglu   = (const float*)d_in[11];
  const float* fn_g   = (const float*)d_in[12];
  const float* fn_b   = (const float*)d_in[13];
  float* out = (float*)d_out;
  float* ws = (float*)d_ws;

  float* X   = ws;                               // 20,480,000 floats
  float* Z   = X + (size_t)NROWS * HH;           // 20,480,000 floats
  float* S   = Z + (size_t)NROWS * HH;           // 10,485,760 floats
  float* Wp  = S + SSIZE;                        // 65,536 floats
  float* Ct2 = Wp + (size_t)NLAYER * PSTRIDE;    // 65,536 floats
  float* WLc = Ct2 + (size_t)NLAYER * PSTRIDE;   // 65,536 floats
  __hip_bfloat16* Wt = (__hip_bfloat16*)(WLc + (size_t)NLAYER * PSTRIDE);  // 524,288 bf16
  __hip_bfloat16* Y  = (__hip_bfloat16*)d_out;   // reuse d_out as bf16 activation scratch

  param_kernel<<<(NLAYER * HH * NN) / 256, 256, 0, stream>>>(log_dt, logA, A_im, Cp, Wp, Ct2, WLc);
  wt_kernel<<<(NLAYER * 512) / 256, 256, 0, stream>>>(Wglu, Wt);
  proj_kernel<<<2048, 256, 0, stream>>>(x, Win, bin, X);

  for (int l = 0; l < NLAYER; l++) {
    ln_kernel<<<NROWS / 4, 256, 0, stream>>>(X, Z, ln_g + l * HH, ln_b + l * HH);
    scanA_kernel<<<dim3(NCH, BB, 4), 256, 0, stream>>>(Z, S, Wp + (size_t)l * PSTRIDE);
    combine_kernel<<<(BB * HH * NN) / 256, 256, 0, stream>>>(S, WLc + (size_t)l * PSTRIDE);
    scanC_kernel<<<dim3(NCH, BB, 4), 256, 0, stream>>>(Z, S, Wp + (size_t)l * PSTRIDE,
                                                       Ct2 + (size_t)l * PSTRIDE, Dv + l * HH, Y);
    gemm_glu_mfma<<<dim3(NROWS / 128, 4), 256, 0, stream>>>(
        Y, Wt + (size_t)l * 512 * HH, bglu + l * 2 * HH, Z, X);
  }
  ln_kernel<<<NROWS / 4, 256, 0, stream>>>(X, out, fn_g, fn_b);
}